// Round 2
// baseline (1317.528 us; speedup 1.0000x reference)
//
#include <hip/hip_runtime.h>
#include <math.h>

// Problem constants (fixed by setup_inputs)
#define BATCH   240
#define SEQ     64
#define HDIM    768
#define NHEADS  12
#define HEADD   64
#define L0LEN   384
#define L1LEN   128
#define LTOT    576      // L0 + L1 + SEQ
#define NTILES  9        // 576 / 64
#define INV_SCALE 0.125f // 1/sqrt(64)

// out layout in d_out: ctx [240*64*768] | k [240*12*64*64] | v [240*12*64*64]
#define OUT_CTX_ELEMS (240*64*768)
#define KV_ELEMS      (240*12*64*64)

// ---------------------------------------------------------------------------
// Kernel 1: QKV projection.  C = X @ W^T + b, X:[15360,768], W:[768,768].
// BM=BN=128, BK=16, 256 threads. 8x8 micro-tile as 2x2 blocks of contiguous
// 4 rows x 4 cols so LDS reads are ds_read_b128 (4 per k-step instead of
// 16 b32 -> ~94% of inner-loop issue slots are FMA).
// LDS k-major, pad 132 floats (528 B = 33*16 -> b128-aligned, <=2-way banks).
// Output written directly in head layout [b][h][s][d].
// grid = (120, 6, 3)  z: 0=q->ws, 1=k->out, 2=v->out
// ---------------------------------------------------------------------------
__global__ __launch_bounds__(256) void qkv_gemm(
    const float* __restrict__ X,
    const float* __restrict__ Wq, const float* __restrict__ bq,
    const float* __restrict__ Wk, const float* __restrict__ bk,
    const float* __restrict__ Wv, const float* __restrict__ bv,
    float* __restrict__ qout, float* __restrict__ kout, float* __restrict__ vout)
{
    __shared__ float As[16][132];
    __shared__ float Bs[16][132];

    const int z = blockIdx.z;
    const float* W    = (z == 0) ? Wq : (z == 1) ? Wk : Wv;
    const float* bias = (z == 0) ? bq : (z == 1) ? bk : bv;
    float* dst        = (z == 0) ? qout : (z == 1) ? kout : vout;

    const int m0  = blockIdx.x * 128;
    const int n0  = blockIdx.y * 128;
    const int tid = threadIdx.x;
    const int tx  = tid & 15;
    const int ty  = tid >> 4;

    float acc[8][8];
#pragma unroll
    for (int i = 0; i < 8; ++i)
#pragma unroll
        for (int j = 0; j < 8; ++j) acc[i][j] = 0.0f;

    for (int kt = 0; kt < HDIM; kt += 16) {
        // Stage A and B tiles transposed to k-major. 2 float4 loads each.
#pragma unroll
        for (int it = 0; it < 2; ++it) {
            const int f   = it * 256 + tid;       // float4 id in [0,512)
            const int row = f >> 2;               // 0..127
            const int c4  = (f & 3) * 4;          // 0,4,8,12
            float4 av = *reinterpret_cast<const float4*>(
                &X[(size_t)(m0 + row) * HDIM + kt + c4]);
            As[c4 + 0][row] = av.x; As[c4 + 1][row] = av.y;
            As[c4 + 2][row] = av.z; As[c4 + 3][row] = av.w;
            float4 bw = *reinterpret_cast<const float4*>(
                &W[(size_t)(n0 + row) * HDIM + kt + c4]);
            Bs[c4 + 0][row] = bw.x; Bs[c4 + 1][row] = bw.y;
            Bs[c4 + 2][row] = bw.z; Bs[c4 + 3][row] = bw.w;
        }
        __syncthreads();

#pragma unroll
        for (int kk = 0; kk < 16; ++kk) {
            const float4 a0 = *reinterpret_cast<const float4*>(&As[kk][ty * 4]);
            const float4 a1 = *reinterpret_cast<const float4*>(&As[kk][64 + ty * 4]);
            const float4 b0 = *reinterpret_cast<const float4*>(&Bs[kk][tx * 4]);
            const float4 b1 = *reinterpret_cast<const float4*>(&Bs[kk][64 + tx * 4]);
            const float a[8] = {a0.x, a0.y, a0.z, a0.w, a1.x, a1.y, a1.z, a1.w};
            const float b[8] = {b0.x, b0.y, b0.z, b0.w, b1.x, b1.y, b1.z, b1.w};
#pragma unroll
            for (int i = 0; i < 8; ++i)
#pragma unroll
                for (int j = 0; j < 8; ++j) acc[i][j] = fmaf(a[i], b[j], acc[i][j]);
        }
        __syncthreads();
    }

    // Epilogue: bias add + float4 store in head layout [b][h][s][d].
    // row m = m0 + (i>>2)*64 + ty*4 + (i&3)  -> b_ = m>>6, s = m&63
    // cols n0 + jb*64 + tx*4 + q             -> h = (n0>>6)+jb, d = tx*4+q
#pragma unroll
    for (int jb = 0; jb < 2; ++jb) {
        const int ncol = n0 + jb * 64 + tx * 4;
        const float4 bb = *reinterpret_cast<const float4*>(&bias[ncol]);
        const int h    = ncol >> 6;
        const int dcol = tx * 4;
#pragma unroll
        for (int i = 0; i < 8; ++i) {
            const int m  = m0 + (i >> 2) * 64 + ty * 4 + (i & 3);
            const int b_ = m >> 6;
            const int s  = m & 63;
            float4 o;
            o.x = acc[i][jb * 4 + 0] + bb.x;
            o.y = acc[i][jb * 4 + 1] + bb.y;
            o.z = acc[i][jb * 4 + 2] + bb.z;
            o.w = acc[i][jb * 4 + 3] + bb.w;
            *reinterpret_cast<float4*>(
                &dst[((((size_t)b_ * NHEADS) + h) * SEQ + s) * HEADD + dcol]) = o;
        }
    }
}

// ---------------------------------------------------------------------------
// Kernel 2: fused cache attention, one block per (b,h) = 2880 blocks.
// Flash-style online softmax over 9 key-tiles of 64:
//   t 0..5 -> c0 (cache batch b%8), t 6..7 -> c1 (batch b), t 8 -> self.
// Q, P staged in LDS; K and V time-share one LDS buffer.
// 256 threads; 4x4 contiguous micro-tile (rows ty*4+i, cols tx*4+j) so all
// inner-loop LDS traffic is ds_read_b128. Pad 68 floats (272 B, b128-aligned).
// ---------------------------------------------------------------------------
__global__ __launch_bounds__(256) void attn_fused(
    const float* __restrict__ qws,    // [240,12,64,64]
    const float* __restrict__ kself,  // [240,12,64,64]
    const float* __restrict__ vself,  // [240,12,64,64]
    const float* __restrict__ c0k, const float* __restrict__ c0v, // [8,12,384,64]
    const float* __restrict__ c1k, const float* __restrict__ c1v, // [240,12,128,64]
    const float* __restrict__ mask,   // [240, 576]
    float* __restrict__ out)          // [240,64,768]
{
    __shared__ float Qs[64][68];
    __shared__ float KVs[64][68];
    __shared__ float Ps[64][68];

    const int bh  = blockIdx.x;
    const int b   = bh / NHEADS;
    const int h   = bh % NHEADS;
    const int tid = threadIdx.x;
    const int tx  = tid & 15;
    const int ty  = tid >> 4;

    // Load Q tile (4096 floats, 4x float4 per thread)
    {
        const float* qp = qws + (size_t)bh * SEQ * HEADD;
#pragma unroll
        for (int it = 0; it < 4; ++it) {
            const int f   = it * 256 + tid;   // float4 id in [0,1024)
            const int row = f >> 4;
            const int c4  = (f & 15) * 4;
            *reinterpret_cast<float4*>(&Qs[row][c4]) =
                *reinterpret_cast<const float4*>(&qp[row * HEADD + c4]);
        }
    }

    float m_run[4], l_run[4], ctx[4][4];
#pragma unroll
    for (int i = 0; i < 4; ++i) {
        m_run[i] = -1e30f;
        l_run[i] = 0.0f;
#pragma unroll
        for (int j = 0; j < 4; ++j) ctx[i][j] = 0.0f;
    }

    for (int t = 0; t < NTILES; ++t) {
        const float* kp;
        const float* vp;
        if (t < 6) {
            const size_t off = ((((size_t)(b & 7)) * NHEADS + h) * L0LEN + t * 64) * HEADD;
            kp = c0k + off; vp = c0v + off;
        } else if (t < 8) {
            const size_t off = (((size_t)b * NHEADS + h) * L1LEN + (t - 6) * 64) * HEADD;
            kp = c1k + off; vp = c1v + off;
        } else {
            const size_t off = (size_t)bh * SEQ * HEADD;
            kp = kself + off; vp = vself + off;
        }

        __syncthreads();   // prev PV done reading KVs/Ps (and Q staged at t=0)

        // Stage K tile
#pragma unroll
        for (int it = 0; it < 4; ++it) {
            const int f   = it * 256 + tid;
            const int row = f >> 4;
            const int c4  = (f & 15) * 4;
            *reinterpret_cast<float4*>(&KVs[row][c4]) =
                *reinterpret_cast<const float4*>(&kp[row * HEADD + c4]);
        }
        __syncthreads();

        // Score phase: sc[i][j] = q[ty*4+i] . k[tx*4+j], d-blocked by 4
        float sc[4][4];
#pragma unroll
        for (int i = 0; i < 4; ++i)
#pragma unroll
            for (int j = 0; j < 4; ++j) sc[i][j] = 0.0f;

#pragma unroll 4
        for (int d0 = 0; d0 < HEADD; d0 += 4) {
            float4 qa[4], ka[4];
#pragma unroll
            for (int i = 0; i < 4; ++i)
                qa[i] = *reinterpret_cast<const float4*>(&Qs[ty * 4 + i][d0]);
#pragma unroll
            for (int j = 0; j < 4; ++j)
                ka[j] = *reinterpret_cast<const float4*>(&KVs[tx * 4 + j][d0]);
#pragma unroll
            for (int i = 0; i < 4; ++i)
#pragma unroll
                for (int j = 0; j < 4; ++j) {
                    sc[i][j] = fmaf(qa[i].x, ka[j].x, sc[i][j]);
                    sc[i][j] = fmaf(qa[i].y, ka[j].y, sc[i][j]);
                    sc[i][j] = fmaf(qa[i].z, ka[j].z, sc[i][j]);
                    sc[i][j] = fmaf(qa[i].w, ka[j].w, sc[i][j]);
                }
        }

        // scale + mask (cols tx*4..tx*4+3 of this tile)
        {
            const float4 m4 = *reinterpret_cast<const float4*>(
                &mask[(size_t)b * LTOT + t * 64 + tx * 4]);
            const float mj[4] = {m4.x, m4.y, m4.z, m4.w};
#pragma unroll
            for (int i = 0; i < 4; ++i)
#pragma unroll
                for (int j = 0; j < 4; ++j)
                    sc[i][j] = fmaf(sc[i][j], INV_SCALE, mj[j]);
        }

        __syncthreads();   // all score reads of KVs done -> safe to overwrite

        // Stage V tile (overwrites KVs)
#pragma unroll
        for (int it = 0; it < 4; ++it) {
            const int f   = it * 256 + tid;
            const int row = f >> 4;
            const int c4  = (f & 15) * 4;
            *reinterpret_cast<float4*>(&KVs[row][c4]) =
                *reinterpret_cast<const float4*>(&vp[row * HEADD + c4]);
        }

        // Online softmax update (registers only; overlaps V staging).
        // Row r = ty*4+i is owned by the 16 lanes sharing ty (contiguous in
        // the wave) -> width-16 shfl_xor reduction.
        float p[4][4];
#pragma unroll
        for (int i = 0; i < 4; ++i) {
            float mt = fmaxf(fmaxf(sc[i][0], sc[i][1]), fmaxf(sc[i][2], sc[i][3]));
            mt = fmaxf(mt, __shfl_xor(mt, 1, 16));
            mt = fmaxf(mt, __shfl_xor(mt, 2, 16));
            mt = fmaxf(mt, __shfl_xor(mt, 4, 16));
            mt = fmaxf(mt, __shfl_xor(mt, 8, 16));
            const float m_new = fmaxf(m_run[i], mt);
            const float scale = __expf(m_run[i] - m_new);
            float lt = 0.0f;
#pragma unroll
            for (int j = 0; j < 4; ++j) {
                p[i][j] = __expf(sc[i][j] - m_new);
                lt += p[i][j];
            }
            lt += __shfl_xor(lt, 1, 16);
            lt += __shfl_xor(lt, 2, 16);
            lt += __shfl_xor(lt, 4, 16);
            lt += __shfl_xor(lt, 8, 16);
            l_run[i] = l_run[i] * scale + lt;
            m_run[i] = m_new;
#pragma unroll
            for (int j = 0; j < 4; ++j) ctx[i][j] *= scale;
        }

        // Publish P tile (float4 stores)
#pragma unroll
        for (int i = 0; i < 4; ++i)
            *reinterpret_cast<float4*>(&Ps[ty * 4 + i][tx * 4]) =
                make_float4(p[i][0], p[i][1], p[i][2], p[i][3]);

        __syncthreads();   // V staged + P published

        // PV phase: ctx[i][j] += sum_k P[ty*4+i][k] * V[k][tx*4+j], k-blocked by 4
#pragma unroll 4
        for (int k0 = 0; k0 < 64; k0 += 4) {
            float4 pa[4];
#pragma unroll
            for (int i = 0; i < 4; ++i)
                pa[i] = *reinterpret_cast<const float4*>(&Ps[ty * 4 + i][k0]);
            const float4 v0 = *reinterpret_cast<const float4*>(&KVs[k0 + 0][tx * 4]);
            const float4 v1 = *reinterpret_cast<const float4*>(&KVs[k0 + 1][tx * 4]);
            const float4 v2 = *reinterpret_cast<const float4*>(&KVs[k0 + 2][tx * 4]);
            const float4 v3 = *reinterpret_cast<const float4*>(&KVs[k0 + 3][tx * 4]);
#pragma unroll
            for (int i = 0; i < 4; ++i) {
                ctx[i][0] = fmaf(pa[i].x, v0.x, fmaf(pa[i].y, v1.x,
                            fmaf(pa[i].z, v2.x, fmaf(pa[i].w, v3.x, ctx[i][0]))));
                ctx[i][1] = fmaf(pa[i].x, v0.y, fmaf(pa[i].y, v1.y,
                            fmaf(pa[i].z, v2.y, fmaf(pa[i].w, v3.y, ctx[i][1]))));
                ctx[i][2] = fmaf(pa[i].x, v0.z, fmaf(pa[i].y, v1.z,
                            fmaf(pa[i].z, v2.z, fmaf(pa[i].w, v3.z, ctx[i][2]))));
                ctx[i][3] = fmaf(pa[i].x, v0.w, fmaf(pa[i].y, v1.w,
                            fmaf(pa[i].z, v2.w, fmaf(pa[i].w, v3.w, ctx[i][3]))));
            }
        }
    }

    // Epilogue: normalize, float4 store ctx -> out[b][q][h*64 + tx*4 ..]
#pragma unroll
    for (int i = 0; i < 4; ++i) {
        const float inv = 1.0f / l_run[i];
        const int q = ty * 4 + i;
        const float4 o = make_float4(ctx[i][0] * inv, ctx[i][1] * inv,
                                     ctx[i][2] * inv, ctx[i][3] * inv);
        *reinterpret_cast<float4*>(
            &out[((size_t)b * SEQ + q) * HDIM + h * HEADD + tx * 4]) = o;
    }
}

// ---------------------------------------------------------------------------
extern "C" void kernel_launch(void* const* d_in, const int* in_sizes, int n_in,
                              void* d_out, int out_size, void* d_ws, size_t ws_size,
                              hipStream_t stream)
{
    const float* X    = (const float*)d_in[0];
    const float* mask = (const float*)d_in[1];
    const float* Wq   = (const float*)d_in[2];
    const float* bq   = (const float*)d_in[3];
    const float* Wk   = (const float*)d_in[4];
    const float* bk   = (const float*)d_in[5];
    const float* Wv   = (const float*)d_in[6];
    const float* bv   = (const float*)d_in[7];
    const float* c0k  = (const float*)d_in[8];
    const float* c0v  = (const float*)d_in[9];
    const float* c1k  = (const float*)d_in[10];
    const float* c1v  = (const float*)d_in[11];
    // d_in[12] = slot_dim (30) -> cache batch mapping b % (240/30) = b % 8.

    float* out  = (float*)d_out;
    float* kout = out + OUT_CTX_ELEMS;
    float* vout = kout + KV_ELEMS;
    float* qws  = (float*)d_ws;   // 983,040 floats = 3.93 MB scratch for q

    qkv_gemm<<<dim3(120, 6, 3), 256, 0, stream>>>(X, Wq, bq, Wk, bk, Wv, bv,
                                                  qws, kout, vout);
    attn_fused<<<dim3(2880), 256, 0, stream>>>(qws, kout, vout,
                                               c0k, c0v, c1k, c1v, mask, out);
}

// Round 3
// 519.103 us; speedup vs baseline: 2.5381x; 2.5381x over previous
//
#include <hip/hip_runtime.h>
#include <math.h>

typedef _Float16 f16;
typedef __attribute__((ext_vector_type(4))) _Float16 f16x4;
typedef __attribute__((ext_vector_type(8))) _Float16 f16x8;
typedef __attribute__((ext_vector_type(4))) float    f32x4;

// Problem constants (fixed by setup_inputs)
#define NHEADS  12
#define SEQ     64
#define HEADD   64
#define HDIM    768
#define LTOT    576
#define INV_SCALE 0.125f

#define OUT_CTX_ELEMS (240*64*768)
#define KV_ELEMS      (240*12*64*64)

// ---------------------------------------------------------------------------
// Kernel 1: QKV projection via fp16 MFMA.  C = X @ W^T + b.
// X:[15360,768] fp32, W:[768,768] fp32. BM=BN=128, BK=32, 256 thr = 4 waves,
// each wave a 64x64 quadrant = 4x4 frags of v_mfma_f32_16x16x32_f16.
// fp32->fp16 conversion fused into LDS staging. LDS stride 40 f16 (80 B):
// b128-aligned, fragment reads 2-way bank aliased (free).
// z=0 writes q as fp16 into ws; z=1/2 write k/v fp32 into d_out (head layout).
// grid = (120, 6, 3)
// ---------------------------------------------------------------------------
__global__ __launch_bounds__(256) void qkv_gemm_mfma(
    const float* __restrict__ X,
    const float* __restrict__ Wq, const float* __restrict__ bq,
    const float* __restrict__ Wk, const float* __restrict__ bk,
    const float* __restrict__ Wv, const float* __restrict__ bv,
    f16* __restrict__ qws, float* __restrict__ kout, float* __restrict__ vout)
{
    __shared__ f16 Ah[128][40];
    __shared__ f16 Bh[128][40];

    const int z = blockIdx.z;
    const float* W    = (z == 0) ? Wq : (z == 1) ? Wk : Wv;
    const float* bias = (z == 0) ? bq : (z == 1) ? bk : bv;

    const int m0 = blockIdx.x * 128;
    const int n0 = blockIdx.y * 128;
    const int tid  = threadIdx.x;
    const int lane = tid & 63;
    const int wave = tid >> 6;
    const int wr = wave >> 1, wc = wave & 1;
    const int lr = lane & 15, lg = lane >> 4;

    const f32x4 zero4 = {0.f, 0.f, 0.f, 0.f};
    f32x4 acc[4][4];
#pragma unroll
    for (int i = 0; i < 4; ++i)
#pragma unroll
        for (int j = 0; j < 4; ++j) acc[i][j] = zero4;

    for (int kt = 0; kt < HDIM; kt += 32) {
        // Stage A (X rows) and B (W rows = C cols), converting to fp16.
#pragma unroll
        for (int it = 0; it < 4; ++it) {
            const int f   = it * 256 + tid;       // float4 id in [0,1024)
            const int row = f >> 3;               // 0..127
            const int c4  = (f & 7) * 4;          // 0..28
            float4 a = *reinterpret_cast<const float4*>(
                &X[(size_t)(m0 + row) * HDIM + kt + c4]);
            f16x4 ah = {(f16)a.x, (f16)a.y, (f16)a.z, (f16)a.w};
            *reinterpret_cast<f16x4*>(&Ah[row][c4]) = ah;
            float4 w4 = *reinterpret_cast<const float4*>(
                &W[(size_t)(n0 + row) * HDIM + kt + c4]);
            f16x4 wh = {(f16)w4.x, (f16)w4.y, (f16)w4.z, (f16)w4.w};
            *reinterpret_cast<f16x4*>(&Bh[row][c4]) = wh;
        }
        __syncthreads();

        // Fragment loads: A[row=lr][k=lg*8+0..7], B[col=lr][k=lg*8+0..7]
        f16x8 af[4], bf[4];
#pragma unroll
        for (int i = 0; i < 4; ++i)
            af[i] = *reinterpret_cast<const f16x8*>(&Ah[wr * 64 + i * 16 + lr][lg * 8]);
#pragma unroll
        for (int j = 0; j < 4; ++j)
            bf[j] = *reinterpret_cast<const f16x8*>(&Bh[wc * 64 + j * 16 + lr][lg * 8]);
#pragma unroll
        for (int i = 0; i < 4; ++i)
#pragma unroll
            for (int j = 0; j < 4; ++j)
                acc[i][j] = __builtin_amdgcn_mfma_f32_16x16x32_f16(
                    af[i], bf[j], acc[i][j], 0, 0, 0);
        __syncthreads();
    }

    // Epilogue. C/D layout: col = lane&15, row = (lane>>4)*4 + reg.
#pragma unroll
    for (int j = 0; j < 4; ++j) {
        const int n  = n0 + wc * 64 + j * 16 + lr;
        const float bb = bias[n];
        const int h = n >> 6, d = n & 63;
#pragma unroll
        for (int i = 0; i < 4; ++i) {
#pragma unroll
            for (int r = 0; r < 4; ++r) {
                const int m  = m0 + wr * 64 + i * 16 + lg * 4 + r;
                const int b_ = m >> 6, s = m & 63;
                const float val = acc[i][j][r] + bb;
                const size_t o  = ((((size_t)b_ * NHEADS) + h) * SEQ + s) * HEADD + d;
                if (z == 0)      qws[o]  = (f16)val;
                else if (z == 1) kout[o] = val;
                else             vout[o] = val;
            }
        }
    }
}

// ---------------------------------------------------------------------------
// Kernel 2: fused cache attention via fp16 MFMA. One block per (b,h) = 2880.
// 4 waves x 16 q-rows each -> softmax fully wave-local (no cross-wave reduce).
// Per 64-key tile: QK^T (A=Q,B=K frags), online softmax in C-fragment regs,
// P round-trips through wave-private LDS (lgkmcnt only, no barrier), PV with
// B-frags from transposed V (staged fp16, stride 68 -> b64-pair reads).
//   t 0..5 -> c0[b%8], t 6..7 -> c1[b], t 8 -> self.
// ---------------------------------------------------------------------------
__global__ __launch_bounds__(256) void attn_mfma(
    const f16*   __restrict__ qws,    // [240,12,64,64] fp16
    const float* __restrict__ kself,  // [240,12,64,64]
    const float* __restrict__ vself,
    const float* __restrict__ c0k, const float* __restrict__ c0v, // [8,12,384,64]
    const float* __restrict__ c1k, const float* __restrict__ c1v, // [240,12,128,64]
    const float* __restrict__ mask,   // [240,576]
    float* __restrict__ out)          // [240,64,768]
{
    __shared__ f16 Qs[64][72];
    __shared__ f16 Ks[64][72];
    __shared__ f16 Ps[64][72];
    __shared__ f16 Vt[64][68];   // [d][key], stride 68 f16 = 136 B (8B-aligned rows)

    const int bh = blockIdx.x;
    const int b  = bh / NHEADS;
    const int h  = bh % NHEADS;
    const int tid  = threadIdx.x;
    const int lane = tid & 63;
    const int wave = tid >> 6;
    const int lr = lane & 15, lg = lane >> 4;
    const int qb = wave * 16;             // this wave's q-row block

    // Stage Q (already fp16 in ws)
    {
        const f16* qp = qws + (size_t)bh * SEQ * HEADD;
#pragma unroll
        for (int it = 0; it < 4; ++it) {
            const int f = it * 256 + tid;
            const int row = f >> 4, c4 = (f & 15) * 4;
            *reinterpret_cast<f16x4*>(&Qs[row][c4]) =
                *reinterpret_cast<const f16x4*>(&qp[row * 64 + c4]);
        }
    }

    const f32x4 zero4 = {0.f, 0.f, 0.f, 0.f};
    f32x4 acc_o[4];
    float m_run[4], l_run[4];
#pragma unroll
    for (int r = 0; r < 4; ++r) { m_run[r] = -1e30f; l_run[r] = 0.f; }
#pragma unroll
    for (int jd = 0; jd < 4; ++jd) acc_o[jd] = zero4;

    for (int t = 0; t < 9; ++t) {
        const float *kp, *vp;
        if (t < 6) {
            const size_t off = ((((size_t)(b & 7)) * NHEADS + h) * 384 + t * 64) * 64;
            kp = c0k + off; vp = c0v + off;
        } else if (t < 8) {
            const size_t off = (((size_t)b * NHEADS + h) * 128 + (t - 6) * 64) * 64;
            kp = c1k + off; vp = c1v + off;
        } else {
            const size_t off = (size_t)bh * SEQ * HEADD;
            kp = kself + off; vp = vself + off;
        }

        __syncthreads();   // prev tile's QK/PV done reading Ks/Vt (Q staged at t=0)

        // Stage K row-major + V transposed, fp32->fp16
#pragma unroll
        for (int it = 0; it < 4; ++it) {
            const int f = it * 256 + tid;
            const int key = f >> 4, d4 = (f & 15) * 4;
            float4 k4 = *reinterpret_cast<const float4*>(&kp[key * 64 + d4]);
            f16x4 kh = {(f16)k4.x, (f16)k4.y, (f16)k4.z, (f16)k4.w};
            *reinterpret_cast<f16x4*>(&Ks[key][d4]) = kh;
            float4 v4 = *reinterpret_cast<const float4*>(&vp[key * 64 + d4]);
            Vt[d4 + 0][key] = (f16)v4.x;
            Vt[d4 + 1][key] = (f16)v4.y;
            Vt[d4 + 2][key] = (f16)v4.z;
            Vt[d4 + 3][key] = (f16)v4.w;
        }
        __syncthreads();

        // QK^T: D[q][key], rows = wave's 16 q-rows, cols = 64 keys (4 j-frags)
        f16x8 aq[2];
#pragma unroll
        for (int kd = 0; kd < 2; ++kd)
            aq[kd] = *reinterpret_cast<const f16x8*>(&Qs[qb + lr][kd * 32 + lg * 8]);
        f32x4 sc[4];
#pragma unroll
        for (int j = 0; j < 4; ++j) {
            sc[j] = zero4;
#pragma unroll
            for (int kd = 0; kd < 2; ++kd) {
                f16x8 bk = *reinterpret_cast<const f16x8*>(
                    &Ks[j * 16 + lr][kd * 32 + lg * 8]);
                sc[j] = __builtin_amdgcn_mfma_f32_16x16x32_f16(aq[kd], bk, sc[j], 0, 0, 0);
            }
        }

        float msk[4];
#pragma unroll
        for (int j = 0; j < 4; ++j)
            msk[j] = mask[(size_t)b * LTOT + t * 64 + j * 16 + lr];

        // Online softmax: lane owns rows qb + lg*4 + r, cols lr + 16j.
        // Row-reduce = in-reg over j + shfl_xor 1/2/4/8 (stays in 16-lane group).
#pragma unroll
        for (int r = 0; r < 4; ++r) {
            float v0 = fmaf(sc[0][r], INV_SCALE, msk[0]);
            float v1 = fmaf(sc[1][r], INV_SCALE, msk[1]);
            float v2 = fmaf(sc[2][r], INV_SCALE, msk[2]);
            float v3 = fmaf(sc[3][r], INV_SCALE, msk[3]);
            float mt = fmaxf(fmaxf(v0, v1), fmaxf(v2, v3));
            mt = fmaxf(mt, __shfl_xor(mt, 1));
            mt = fmaxf(mt, __shfl_xor(mt, 2));
            mt = fmaxf(mt, __shfl_xor(mt, 4));
            mt = fmaxf(mt, __shfl_xor(mt, 8));
            const float m_new = fmaxf(m_run[r], mt);
            const float scl   = __expf(m_run[r] - m_new);
            float p0 = __expf(v0 - m_new), p1 = __expf(v1 - m_new);
            float p2 = __expf(v2 - m_new), p3 = __expf(v3 - m_new);
            float lt = p0 + p1 + p2 + p3;
            lt += __shfl_xor(lt, 1);
            lt += __shfl_xor(lt, 2);
            lt += __shfl_xor(lt, 4);
            lt += __shfl_xor(lt, 8);
            l_run[r] = l_run[r] * scl + lt;
            m_run[r] = m_new;
#pragma unroll
            for (int jd = 0; jd < 4; ++jd) acc_o[jd][r] *= scl;
            const int prow = qb + lg * 4 + r;
            Ps[prow][ 0 + lr] = (f16)p0;
            Ps[prow][16 + lr] = (f16)p1;
            Ps[prow][32 + lr] = (f16)p2;
            Ps[prow][48 + lr] = (f16)p3;
        }

        // P is wave-private (rows qb..qb+15): drain ds_writes, no barrier needed.
        __asm__ volatile("s_waitcnt lgkmcnt(0)" ::: "memory");

        // PV: D[q][d] += P[q][key] * V[key][d];  A=P-frag, B=Vt-frag (col=d,k=key)
        f16x8 ap[2];
#pragma unroll
        for (int ks = 0; ks < 2; ++ks)
            ap[ks] = *reinterpret_cast<const f16x8*>(&Ps[qb + lr][ks * 32 + lg * 8]);
#pragma unroll
        for (int jd = 0; jd < 4; ++jd) {
#pragma unroll
            for (int ks = 0; ks < 2; ++ks) {
                f16x4 lo = *reinterpret_cast<const f16x4*>(
                    &Vt[jd * 16 + lr][ks * 32 + lg * 8]);
                f16x4 hi = *reinterpret_cast<const f16x4*>(
                    &Vt[jd * 16 + lr][ks * 32 + lg * 8 + 4]);
                f16x8 bv = __builtin_shufflevector(lo, hi, 0, 1, 2, 3, 4, 5, 6, 7);
                acc_o[jd] = __builtin_amdgcn_mfma_f32_16x16x32_f16(
                    ap[ks], bv, acc_o[jd], 0, 0, 0);
            }
        }
    }

    // Epilogue: normalize, store out[b][q][h*64+d]
#pragma unroll
    for (int r = 0; r < 4; ++r) {
        const float inv = 1.0f / l_run[r];
        const int q = qb + lg * 4 + r;
#pragma unroll
        for (int jd = 0; jd < 4; ++jd) {
            out[((size_t)b * SEQ + q) * HDIM + h * HEADD + jd * 16 + lr] =
                acc_o[jd][r] * inv;
        }
    }
}

// ---------------------------------------------------------------------------
extern "C" void kernel_launch(void* const* d_in, const int* in_sizes, int n_in,
                              void* d_out, int out_size, void* d_ws, size_t ws_size,
                              hipStream_t stream)
{
    const float* X    = (const float*)d_in[0];
    const float* mask = (const float*)d_in[1];
    const float* Wq   = (const float*)d_in[2];
    const float* bq   = (const float*)d_in[3];
    const float* Wk   = (const float*)d_in[4];
    const float* bk   = (const float*)d_in[5];
    const float* Wv   = (const float*)d_in[6];
    const float* bv   = (const float*)d_in[7];
    const float* c0k  = (const float*)d_in[8];
    const float* c0v  = (const float*)d_in[9];
    const float* c1k  = (const float*)d_in[10];
    const float* c1v  = (const float*)d_in[11];
    // d_in[12] = slot_dim (30) -> cache batch mapping b % (240/30) = b % 8.

    float* out  = (float*)d_out;
    float* kout = out + OUT_CTX_ELEMS;
    float* vout = kout + KV_ELEMS;
    f16*   qws  = (f16*)d_ws;   // 983,040 f16 = 1.97 MB scratch for q

    qkv_gemm_mfma<<<dim3(120, 6, 3), 256, 0, stream>>>(X, Wq, bq, Wk, bk, Wv, bv,
                                                       qws, kout, vout);
    attn_mfma<<<dim3(2880), 256, 0, stream>>>(qws, kout, vout,
                                              c0k, c0v, c1k, c1v, mask, out);
}